// Round 7
// baseline (304.220 us; speedup 1.0000x reference)
//
#include <hip/hip_runtime.h>
#include <hip/hip_bf16.h>

// IWHT3Layer: 3 branches of (per-coeff matmul [16,12544,64]x[16,64,64]) +
// inverse 2D 4x4 WHT over the 16 coefficients + bias.
// Inputs: float32. Output: float32.
//
// R11 change vs R10 (7 schedule variants all 100-112us, every pipe idle):
// traffic accounting shows the wall is plausibly in the CACHE HIERARCHY, not
// the CU: working set 154MB in + 154MB out = 308MB > 256MB L3, so the output
// write stream evicts half the input every iteration (FETCH_SIZE 77MB = half
// the logical 154MB reads). Two changes on the verified R9 base:
//  (1) NONTEMPORAL stores (nt flag): output bypasses cache allocation ->
//      input stays L3-resident across iterations (readout: FETCH_SIZE).
//  (2) Whole-tile staging, 2 phases: all 16 planes (64KB) staged up front as
//      16 width-16 DMAs/wave (order: planes 0-7 then 8-15, pinned);
//      vmcnt(8) -> compute t=0..7; vmcnt(0) -> compute t=8..15. Only 2
//      barriers per tile (was 8), zero mid-loop VMEM (wf in regs, R9),
//      maximum burst per wave (readout: dur beyond the FETCH effect).
// wf-hoist ordering (all weight loads issued BEFORE DMAs, in-order vmcnt per
// m135), XOR-swizzled width-16 DMA staging, LDS read swizzle, MFMA operand
// order, WHT and epilogue math byte-identical to verified R9.

typedef __attribute__((ext_vector_type(8))) short bf16x8;   // 8 bf16 (4 VGPRs)
typedef __attribute__((ext_vector_type(4))) float floatx4;  // MFMA C/D

#define NSITES 12544
#define NTILES 784
#define OUT_PER_BRANCH 12845056  // 16*112*112*64
#define WT_ELEMS (3*16*64*64)

__device__ __forceinline__ short f32_to_bf16_bits(float f) {
    __hip_bfloat16 h = __float2bfloat16(f);  // RNE
    return *reinterpret_cast<short*>(&h);
}

__global__ void transpose_weights(const float* __restrict__ w0,
                                  const float* __restrict__ w1,
                                  const float* __restrict__ w2,
                                  __hip_bfloat16* __restrict__ wT) {
    int idx = blockIdx.x * blockDim.x + threadIdx.x;  // [0, 3*16*64*64)
    if (idx >= WT_ELEMS) return;
    int c  = idx & 63;
    int k  = (idx >> 6) & 63;
    int t  = (idx >> 12) & 15;
    int br = idx >> 16;
    const float* w = (br == 0) ? w0 : ((br == 1) ? w1 : w2);
    // wT[br][t][k][c] = bf16(w[br][t][c][k])
    wT[idx] = __float2bfloat16(w[(t * 64 + c) * 64 + k]);
}

template <bool USE_WT>
__global__ __launch_bounds__(256, 2) void iwht_kernel(
    const float* __restrict__ x0, const float* __restrict__ x1,
    const float* __restrict__ x2,
    const float* __restrict__ w0, const float* __restrict__ w1,
    const float* __restrict__ w2,
    const __hip_bfloat16* __restrict__ wT,
    const float* __restrict__ b0, const float* __restrict__ b1,
    const float* __restrict__ b2,
    float* __restrict__ out) {
    // Whole tile: 16 planes x 16 rows x 64 floats = 65536 B.
    __shared__ float xs[16 * 16 * 64];

    int bx   = blockIdx.x;
    int br   = bx / NTILES;
    int tile = bx - br * NTILES;
    int lane = threadIdx.x & 63;
    int wave = threadIdx.x >> 6;
    int l15  = lane & 15;
    int quad = lane >> 4;
    int n    = wave * 16 + l15;  // weight-fragment row: output channel block

    const float* x    = (br == 0) ? x0 : ((br == 1) ? x1 : x2);
    const float* w    = (br == 0) ? w0 : ((br == 1) ? w1 : w2);
    const float* bias = (br == 0) ? b0 : ((br == 1) ? b1 : b2);

    // Width-16 DMA lane decomposition: inst covers 4 site-rows (1KB);
    // lane serves sub-row (lane>>4), 16B column (lane&15), XOR-swizzled
    // source so the linear LDS dest ends up swizzle-stored (rule #21).
    int sub  = lane >> 4;   // 0..3: which of the 4 rows in this inst
    int lcol = lane & 15;   // 16B column within the 256B row

    int k0 = wave * 16 + quad * 4;

    floatx4 acc[16];
#pragma unroll
    for (int t = 0; t < 16; t++) acc[t] = (floatx4){0.f, 0.f, 0.f, 0.f};

    // --- bias + ALL weight fragments into registers, issued BEFORE any DMA
    // so the counted vmcnt waits cover them (in-order retirement, m135). ---
    floatx4 bias4 = *reinterpret_cast<const floatx4*>(bias + k0);
    bf16x8 wf[32];
    if (USE_WT) {
#pragma unroll
        for (int t = 0; t < 16; t++) {
            const bf16x8* wv = reinterpret_cast<const bf16x8*>(
                wT + (((size_t)(br * 16 + t) * 64 + n) * 64) + quad * 8);
            wf[2 * t]     = wv[0];
            wf[2 * t + 1] = wv[4];  // +32 c elements
        }
    } else {
#pragma unroll
        for (int t = 0; t < 16; t++) {
#pragma unroll
            for (int j = 0; j < 8; j++) {
                int c0 = quad * 8 + j;
                wf[2 * t][j]     = f32_to_bf16_bits(w[(t * 64 + c0) * 64 + n]);
                wf[2 * t + 1][j] = f32_to_bf16_bits(w[(t * 64 + c0 + 32) * 64 + n]);
            }
        }
    }
    __builtin_amdgcn_sched_barrier(0);  // pin bias+wf loads before the DMAs

    // --- stage planes of half h (g = 2h, 2h+1; plane = 4g+wave): 8 width-16
    // DMAs/wave, source XOR-pre-swizzled, LDS dest linear. ---
#define STAGEHALF(h)                                                           \
    {                                                                          \
        _Pragma("unroll") for (int g = 2 * (h); g < 2 * (h) + 2; ++g) {        \
            _Pragma("unroll") for (int r = 0; r < 4; r++) {                    \
                int s   = 4 * r + sub;      /* site row within plane */        \
                int col = lcol ^ (s & 7);   /* swizzled 16B column   */        \
                const float* gp = x +                                          \
                    ((size_t)(g * 4 + wave) * NSITES + tile * 16 + s) * 64 +   \
                    col * 4;                                                   \
                __builtin_amdgcn_global_load_lds(                              \
                    (const __attribute__((address_space(1))) void*)gp,         \
                    (__attribute__((address_space(3))) void*)                  \
                        &xs[((g * 4 + wave) * 16 + 4 * r) * 64],               \
                    16, 0, 0);                                                 \
            }                                                                  \
        }                                                                      \
        __builtin_amdgcn_sched_barrier(0);                                     \
    }

    // --- compute half h (t = 8h..8h+7): weights from wf regs, ZERO VMEM.
    // Read with the store-side XOR: logical col c of row l15 at c ^ (l15&7).
#define COMPUTEHALF(h)                                                         \
    {                                                                          \
        int xr7 = l15 & 7;                                                     \
        _Pragma("unroll") for (int tl = 0; tl < 8; tl++) {                     \
            int t = 8 * (h) + tl;                                              \
            const float* rp = &xs[(t * 16 + l15) * 64];                        \
            floatx4 f0 = *(const floatx4*)(rp + ((quad * 2) ^ xr7) * 4);       \
            floatx4 f1 = *(const floatx4*)(rp + ((quad * 2 + 1) ^ xr7) * 4);   \
            floatx4 f2 = *(const floatx4*)(rp + (((quad * 2) ^ xr7) + 8) * 4); \
            floatx4 f3 = *(const floatx4*)(rp + (((quad * 2 + 1) ^ xr7) + 8) * 4); \
            bf16x8 a0, a1;                                                     \
            _Pragma("unroll") for (int j = 0; j < 4; j++) {                    \
                a0[j]     = f32_to_bf16_bits(f0[j]);                           \
                a0[j + 4] = f32_to_bf16_bits(f1[j]);                           \
                a1[j]     = f32_to_bf16_bits(f2[j]);                           \
                a1[j + 4] = f32_to_bf16_bits(f3[j]);                           \
            }                                                                  \
            acc[t] = __builtin_amdgcn_mfma_f32_16x16x32_bf16(wf[2 * t], a0,    \
                                                             acc[t], 0, 0, 0); \
            acc[t] = __builtin_amdgcn_mfma_f32_16x16x32_bf16(wf[2 * t + 1], a1,\
                                                             acc[t], 0, 0, 0); \
        }                                                                      \
    }

#define WAITV(N)                                                               \
    asm volatile("s_waitcnt vmcnt(" #N ")" ::: "memory");                      \
    __builtin_amdgcn_s_barrier();                                              \
    __builtin_amdgcn_sched_barrier(0);

    // Stage the whole 64KB tile: planes 0-7 first, then 8-15 (order pinned).
    STAGEHALF(0);
    STAGEHALF(1);

    // Half A ready when <=8 of our (32 wf + 16 stage) ops remain outstanding.
    WAITV(8);
    COMPUTEHALF(0);

    // Half B (issued 1 compute-half ago) fully landed.
    WAITV(0);
    COMPUTEHALF(1);

#undef STAGEHALF
#undef COMPUTEHALF
#undef WAITV

    // Epilogue: one site per thread, 4 consecutive k per reg.
    int site = tile * 16 + l15;
    int b    = site / 784;
    int rem  = site - b * 784;
    int i    = rem / 28;
    int j    = rem - i * 28;
    float* op = out + (size_t)br * OUT_PER_BRANCH +
                (((size_t)(b * 112 + 4 * i)) * 112 + 4 * j) * 64 + k0;

    // Inverse WHT over v (t = 4u+v): acc[4u+q] = sum_v H[q][v] y[4u+v]
#pragma unroll
    for (int u = 0; u < 4; u++) {
        floatx4 y0 = acc[4 * u + 0], y1 = acc[4 * u + 1];
        floatx4 y2 = acc[4 * u + 2], y3 = acc[4 * u + 3];
        floatx4 A = y0 + y2, Bv = y1 + y3, Cv = y0 - y2, Dv = y1 - y3;
        acc[4 * u + 0] = A + Bv;
        acc[4 * u + 1] = A - Bv;
        acc[4 * u + 2] = Cv + Dv;
        acc[4 * u + 3] = Cv - Dv;
    }

    // Inverse WHT over u, then scale + bias + NONTEMPORAL dwordx4 stores
    // (nt: bypass cache allocation -> keep the input L3-resident).
#pragma unroll
    for (int q = 0; q < 4; q++) {
        floatx4 z0 = acc[0 + q], z1 = acc[4 + q], z2 = acc[8 + q], z3 = acc[12 + q];
        floatx4 A = z0 + z2, Bv = z1 + z3, Cv = z0 - z2, Dv = z1 - z3;
        floatx4 o[4];
        o[0] = A + Bv;
        o[1] = A - Bv;
        o[2] = Cv + Dv;
        o[3] = Cv - Dv;
#pragma unroll
        for (int p = 0; p < 4; p++) {
            floatx4 v = o[p] * 0.0625f + bias4;
            __builtin_nontemporal_store(
                v, reinterpret_cast<floatx4*>(op + (size_t)(p * 112 + q) * 64));
        }
    }
}

extern "C" void kernel_launch(void* const* d_in, const int* in_sizes, int n_in,
                              void* d_out, int out_size, void* d_ws, size_t ws_size,
                              hipStream_t stream) {
    const float* x0 = (const float*)d_in[0];
    const float* x1 = (const float*)d_in[1];
    const float* x2 = (const float*)d_in[2];
    const float* w0 = (const float*)d_in[3];
    const float* w1 = (const float*)d_in[4];
    const float* w2 = (const float*)d_in[5];
    const float* b0 = (const float*)d_in[6];
    const float* b1 = (const float*)d_in[7];
    const float* b2 = (const float*)d_in[8];
    float* out = (float*)d_out;
    __hip_bfloat16* wT = (__hip_bfloat16*)d_ws;

    bool use_wt = ws_size >= (size_t)WT_ELEMS * sizeof(__hip_bfloat16);
    if (use_wt) {
        transpose_weights<<<(WT_ELEMS + 255) / 256, 256, 0, stream>>>(w0, w1, w2, wT);
        iwht_kernel<true><<<3 * NTILES, 256, 0, stream>>>(x0, x1, x2, w0, w1, w2, wT,
                                                          b0, b1, b2, out);
    } else {
        iwht_kernel<false><<<3 * NTILES, 256, 0, stream>>>(x0, x1, x2, w0, w1, w2, wT,
                                                           b0, b1, b2, out);
    }
}

// Round 8
// 295.634 us; speedup vs baseline: 1.0290x; 1.0290x over previous
//
#include <hip/hip_runtime.h>
#include <hip/hip_bf16.h>

// IWHT3Layer: 3 branches of (per-coeff matmul [16,12544,64]x[16,64,64]) +
// inverse 2D 4x4 WHT over the 16 coefficients + bias.
// Inputs: float32. Output: float32.
//
// R12 change vs R11 (8 rounds: load-side schedule fully exonerated, all
// variants 100-112us with every CU pipe idle; R11's nt-store probe showed
// the WRITE path is the sensitive half — WRITE_SIZE 151->203MB when 64B
// segment merging was bypassed): every previous version stored 16 scattered
// 64B segments per wave-inst (each thread owns 4 channels x 16 pixels).
// Known-good ~5TB/s streaming kernels on this chip write 1KB contiguous per
// wave-inst. Fix: LDS OUTPUT BOUNCE. After compute, the tile's 64KB output
// is written to LDS (reusing xs after a barrier) with a slot^site XOR
// (conflict-free: structural 8-phase minimum on both b128 sides), then each
// wave re-reads 16 (site,p) rows and issues 16 global_store_dwordx4 that are
// each ONE contiguous 1KB segment (4 q-pixels x 64ch). Same store count,
// same bytes — only the per-inst address shape changes. nt removed (R11:
// harmful). Load side (whole-tile width-16 swizzled DMA, wf-hoist ordering,
// counted vmcnt per m135), MFMA operands, WHT math byte-identical to R11.

typedef __attribute__((ext_vector_type(8))) short bf16x8;   // 8 bf16 (4 VGPRs)
typedef __attribute__((ext_vector_type(4))) float floatx4;  // MFMA C/D

#define NSITES 12544
#define NTILES 784
#define OUT_PER_BRANCH 12845056  // 16*112*112*64
#define WT_ELEMS (3*16*64*64)

__device__ __forceinline__ short f32_to_bf16_bits(float f) {
    __hip_bfloat16 h = __float2bfloat16(f);  // RNE
    return *reinterpret_cast<short*>(&h);
}

__global__ void transpose_weights(const float* __restrict__ w0,
                                  const float* __restrict__ w1,
                                  const float* __restrict__ w2,
                                  __hip_bfloat16* __restrict__ wT) {
    int idx = blockIdx.x * blockDim.x + threadIdx.x;  // [0, 3*16*64*64)
    if (idx >= WT_ELEMS) return;
    int c  = idx & 63;
    int k  = (idx >> 6) & 63;
    int t  = (idx >> 12) & 15;
    int br = idx >> 16;
    const float* w = (br == 0) ? w0 : ((br == 1) ? w1 : w2);
    // wT[br][t][k][c] = bf16(w[br][t][c][k])
    wT[idx] = __float2bfloat16(w[(t * 64 + c) * 64 + k]);
}

template <bool USE_WT>
__global__ __launch_bounds__(256, 2) void iwht_kernel(
    const float* __restrict__ x0, const float* __restrict__ x1,
    const float* __restrict__ x2,
    const float* __restrict__ w0, const float* __restrict__ w1,
    const float* __restrict__ w2,
    const __hip_bfloat16* __restrict__ wT,
    const float* __restrict__ b0, const float* __restrict__ b1,
    const float* __restrict__ b2,
    float* __restrict__ out) {
    // Whole x tile: 16 planes x 16 rows x 64 floats = 65536 B.
    // Reused after compute as the output bounce buffer:
    // 256 rows (site,p,q) x 64 ch floats = 65536 B.
    __shared__ float xs[16 * 16 * 64];

    int bx   = blockIdx.x;
    int br   = bx / NTILES;
    int tile = bx - br * NTILES;
    int lane = threadIdx.x & 63;
    int wave = threadIdx.x >> 6;
    int l15  = lane & 15;
    int quad = lane >> 4;
    int n    = wave * 16 + l15;  // weight-fragment row: output channel block

    const float* x    = (br == 0) ? x0 : ((br == 1) ? x1 : x2);
    const float* w    = (br == 0) ? w0 : ((br == 1) ? w1 : w2);
    const float* bias = (br == 0) ? b0 : ((br == 1) ? b1 : b2);
    float* outb = out + (size_t)br * OUT_PER_BRANCH;

    // Width-16 DMA lane decomposition: inst covers 4 site-rows (1KB);
    // lane serves sub-row (lane>>4), 16B column (lane&15), XOR-swizzled
    // source so the linear LDS dest ends up swizzle-stored (rule #21).
    int sub  = lane >> 4;   // 0..3: which of the 4 rows in this inst
    int lcol = lane & 15;   // 16B column within the 256B row

    int k0 = wave * 16 + quad * 4;

    floatx4 acc[16];
#pragma unroll
    for (int t = 0; t < 16; t++) acc[t] = (floatx4){0.f, 0.f, 0.f, 0.f};

    // --- bias + ALL weight fragments into registers, issued BEFORE any DMA
    // so the counted vmcnt waits cover them (in-order retirement, m135). ---
    floatx4 bias4 = *reinterpret_cast<const floatx4*>(bias + k0);
    bf16x8 wf[32];
    if (USE_WT) {
#pragma unroll
        for (int t = 0; t < 16; t++) {
            const bf16x8* wv = reinterpret_cast<const bf16x8*>(
                wT + (((size_t)(br * 16 + t) * 64 + n) * 64) + quad * 8);
            wf[2 * t]     = wv[0];
            wf[2 * t + 1] = wv[4];  // +32 c elements
        }
    } else {
#pragma unroll
        for (int t = 0; t < 16; t++) {
#pragma unroll
            for (int j = 0; j < 8; j++) {
                int c0 = quad * 8 + j;
                wf[2 * t][j]     = f32_to_bf16_bits(w[(t * 64 + c0) * 64 + n]);
                wf[2 * t + 1][j] = f32_to_bf16_bits(w[(t * 64 + c0 + 32) * 64 + n]);
            }
        }
    }
    __builtin_amdgcn_sched_barrier(0);  // pin bias+wf loads before the DMAs

    // --- stage planes of half h (g = 2h, 2h+1; plane = 4g+wave): 8 width-16
    // DMAs/wave, source XOR-pre-swizzled, LDS dest linear. ---
#define STAGEHALF(h)                                                           \
    {                                                                          \
        _Pragma("unroll") for (int g = 2 * (h); g < 2 * (h) + 2; ++g) {        \
            _Pragma("unroll") for (int r = 0; r < 4; r++) {                    \
                int s   = 4 * r + sub;      /* site row within plane */        \
                int col = lcol ^ (s & 7);   /* swizzled 16B column   */        \
                const float* gp = x +                                          \
                    ((size_t)(g * 4 + wave) * NSITES + tile * 16 + s) * 64 +   \
                    col * 4;                                                   \
                __builtin_amdgcn_global_load_lds(                              \
                    (const __attribute__((address_space(1))) void*)gp,         \
                    (__attribute__((address_space(3))) void*)                  \
                        &xs[((g * 4 + wave) * 16 + 4 * r) * 64],               \
                    16, 0, 0);                                                 \
            }                                                                  \
        }                                                                      \
        __builtin_amdgcn_sched_barrier(0);                                     \
    }

    // --- compute half h (t = 8h..8h+7): weights from wf regs, ZERO VMEM.
    // Read with the store-side XOR: logical col c of row l15 at c ^ (l15&7).
#define COMPUTEHALF(h)                                                         \
    {                                                                          \
        int xr7 = l15 & 7;                                                     \
        _Pragma("unroll") for (int tl = 0; tl < 8; tl++) {                     \
            int t = 8 * (h) + tl;                                              \
            const float* rp = &xs[(t * 16 + l15) * 64];                        \
            floatx4 f0 = *(const floatx4*)(rp + ((quad * 2) ^ xr7) * 4);       \
            floatx4 f1 = *(const floatx4*)(rp + ((quad * 2 + 1) ^ xr7) * 4);   \
            floatx4 f2 = *(const floatx4*)(rp + (((quad * 2) ^ xr7) + 8) * 4); \
            floatx4 f3 = *(const floatx4*)(rp + (((quad * 2 + 1) ^ xr7) + 8) * 4); \
            bf16x8 a0, a1;                                                     \
            _Pragma("unroll") for (int j = 0; j < 4; j++) {                    \
                a0[j]     = f32_to_bf16_bits(f0[j]);                           \
                a0[j + 4] = f32_to_bf16_bits(f1[j]);                           \
                a1[j]     = f32_to_bf16_bits(f2[j]);                           \
                a1[j + 4] = f32_to_bf16_bits(f3[j]);                           \
            }                                                                  \
            acc[t] = __builtin_amdgcn_mfma_f32_16x16x32_bf16(wf[2 * t], a0,    \
                                                             acc[t], 0, 0, 0); \
            acc[t] = __builtin_amdgcn_mfma_f32_16x16x32_bf16(wf[2 * t + 1], a1,\
                                                             acc[t], 0, 0, 0); \
        }                                                                      \
    }

#define WAITV(N)                                                               \
    asm volatile("s_waitcnt vmcnt(" #N ")" ::: "memory");                      \
    __builtin_amdgcn_s_barrier();                                              \
    __builtin_amdgcn_sched_barrier(0);

    // Stage the whole 64KB tile: planes 0-7 first, then 8-15 (order pinned).
    STAGEHALF(0);
    STAGEHALF(1);

    // Half A ready when <=8 VMEM ops remain outstanding (wf all older).
    WAITV(8);
    COMPUTEHALF(0);

    // Half B fully landed.
    WAITV(0);
    COMPUTEHALF(1);

#undef STAGEHALF
#undef COMPUTEHALF
#undef WAITV

    // ================= Epilogue: WHT -> LDS bounce -> 1KB stores ===========

    // Inverse WHT over v (t = 4u+v): acc[4u+q] = sum_v H[q][v] y[4u+v]
#pragma unroll
    for (int u = 0; u < 4; u++) {
        floatx4 y0 = acc[4 * u + 0], y1 = acc[4 * u + 1];
        floatx4 y2 = acc[4 * u + 2], y3 = acc[4 * u + 3];
        floatx4 A = y0 + y2, Bv = y1 + y3, Cv = y0 - y2, Dv = y1 - y3;
        acc[4 * u + 0] = A + Bv;
        acc[4 * u + 1] = A - Bv;
        acc[4 * u + 2] = Cv + Dv;
        acc[4 * u + 3] = Cv - Dv;
    }

    // All waves done reading xs -> safe to reuse as the output bounce.
    __syncthreads();

    // Inverse WHT over u, scale + bias, write to LDS bounce.
    // Row (site=l15, p, q) holds the pixel's 64 channels; this thread owns
    // k-slot (wave*4+quad), stored at physical slot (slot ^ site) —
    // conflict-free (structural 8-phase b128 on both sides).
    int slotw = wave * 4 + quad;
#pragma unroll
    for (int q = 0; q < 4; q++) {
        floatx4 z0 = acc[0 + q], z1 = acc[4 + q], z2 = acc[8 + q], z3 = acc[12 + q];
        floatx4 A = z0 + z2, Bv = z1 + z3, Cv = z0 - z2, Dv = z1 - z3;
        floatx4 o[4];
        o[0] = A + Bv;
        o[1] = A - Bv;
        o[2] = Cv + Dv;
        o[3] = Cv - Dv;
#pragma unroll
        for (int p = 0; p < 4; p++) {
            floatx4 v = o[p] * 0.0625f + bias4;
            *reinterpret_cast<floatx4*>(
                &xs[((l15 * 4 + p) * 4 + q) * 64 + ((slotw ^ l15) << 2)]) = v;
        }
    }
    __syncthreads();

    // Contiguous stores: wave handles 16 (site,p) units; each inst is one
    // 1KB contiguous segment (lane l: q = l>>4, ch-slot = l&15 -> +4*lane).
    int slotr = lane & 15;
    int qr    = lane >> 4;
#pragma unroll
    for (int uu = 0; uu < 16; uu++) {
        int sloc = wave * 4 + (uu & 3);  // site within tile (inner: adjacent)
        int p    = uu >> 2;
        int site = tile * 16 + sloc;
        int b    = site / 784;
        int rem  = site - b * 784;
        int i    = rem / 28;
        int j    = rem - i * 28;
        floatx4 v = *reinterpret_cast<const floatx4*>(
            &xs[((sloc * 4 + p) * 4 + qr) * 64 + ((slotr ^ sloc) << 2)]);
        float* dst = outb +
            (((size_t)(b * 112 + 4 * i + p)) * 112 + 4 * j) * 64 + lane * 4;
        *reinterpret_cast<floatx4*>(dst) = v;
    }
}

extern "C" void kernel_launch(void* const* d_in, const int* in_sizes, int n_in,
                              void* d_out, int out_size, void* d_ws, size_t ws_size,
                              hipStream_t stream) {
    const float* x0 = (const float*)d_in[0];
    const float* x1 = (const float*)d_in[1];
    const float* x2 = (const float*)d_in[2];
    const float* w0 = (const float*)d_in[3];
    const float* w1 = (const float*)d_in[4];
    const float* w2 = (const float*)d_in[5];
    const float* b0 = (const float*)d_in[6];
    const float* b1 = (const float*)d_in[7];
    const float* b2 = (const float*)d_in[8];
    float* out = (float*)d_out;
    __hip_bfloat16* wT = (__hip_bfloat16*)d_ws;

    bool use_wt = ws_size >= (size_t)WT_ELEMS * sizeof(__hip_bfloat16);
    if (use_wt) {
        transpose_weights<<<(WT_ELEMS + 255) / 256, 256, 0, stream>>>(w0, w1, w2, wT);
        iwht_kernel<true><<<3 * NTILES, 256, 0, stream>>>(x0, x1, x2, w0, w1, w2, wT,
                                                          b0, b1, b2, out);
    } else {
        iwht_kernel<false><<<3 * NTILES, 256, 0, stream>>>(x0, x1, x2, w0, w1, w2, wT,
                                                           b0, b1, b2, out);
    }
}

// Round 9
// 292.257 us; speedup vs baseline: 1.0409x; 1.0116x over previous
//
#include <hip/hip_runtime.h>
#include <hip/hip_bf16.h>

// IWHT3Layer: 3 branches of (per-coeff matmul [16,12544,64]x[16,64,64]) +
// inverse 2D 4x4 WHT over the 16 coefficients + bias.
// Inputs: float32. Output: float32.
//
// R13 change vs R12 (103us; ledger: load schedule x7, store shape, occupancy,
// persistence, barriers ALL null at ~2.3TB/s with every CU pipe idle): the
// one never-swapped component on the critical path is the global_load_lds
// DMA instrument itself. HK precedent: reg-staging (global->reg->ds_write)
// is their preferred pattern; m97's DMA throughput was only ever measured on
// L2-resident staging, never HBM streaming. R6's apparent refutation of
// direct loads was confounded (VGPR=48 -> 2-deep pipeline + 256B-strided
// lanes). THIS round swaps ONLY the instrument:
//   16 global_load_dwordx4/wave (same 1KB/inst footprint, same addresses)
//   -> registers -> ds_write_b128 into the SAME swizzled LDS layout
//   (swizzle moves from the global source address to the ds_write address;
//   compute read path byte-identical).
// Wait structure identical counts: wf(32)+x(16) in order; vmcnt(8) ->
// write planes 0-7 -> lgkmcnt(0)+barrier -> compute half0 (x half B still in
// flight) -> vmcnt(0) -> write planes 8-15 -> barrier -> half1. acc zero-init
// moved after staging (peak VGPR ~235, no spill). Epilogue (WHT -> LDS
// bounce -> 1KB contiguous stores, WRITE_SIZE bit-exact) identical to R12.

typedef __attribute__((ext_vector_type(8))) short bf16x8;   // 8 bf16 (4 VGPRs)
typedef __attribute__((ext_vector_type(4))) float floatx4;  // MFMA C/D

#define NSITES 12544
#define NTILES 784
#define OUT_PER_BRANCH 12845056  // 16*112*112*64
#define WT_ELEMS (3*16*64*64)

__device__ __forceinline__ short f32_to_bf16_bits(float f) {
    __hip_bfloat16 h = __float2bfloat16(f);  // RNE
    return *reinterpret_cast<short*>(&h);
}

__global__ void transpose_weights(const float* __restrict__ w0,
                                  const float* __restrict__ w1,
                                  const float* __restrict__ w2,
                                  __hip_bfloat16* __restrict__ wT) {
    int idx = blockIdx.x * blockDim.x + threadIdx.x;  // [0, 3*16*64*64)
    if (idx >= WT_ELEMS) return;
    int c  = idx & 63;
    int k  = (idx >> 6) & 63;
    int t  = (idx >> 12) & 15;
    int br = idx >> 16;
    const float* w = (br == 0) ? w0 : ((br == 1) ? w1 : w2);
    // wT[br][t][k][c] = bf16(w[br][t][c][k])
    wT[idx] = __float2bfloat16(w[(t * 64 + c) * 64 + k]);
}

template <bool USE_WT>
__global__ __launch_bounds__(256, 2) void iwht_kernel(
    const float* __restrict__ x0, const float* __restrict__ x1,
    const float* __restrict__ x2,
    const float* __restrict__ w0, const float* __restrict__ w1,
    const float* __restrict__ w2,
    const __hip_bfloat16* __restrict__ wT,
    const float* __restrict__ b0, const float* __restrict__ b1,
    const float* __restrict__ b2,
    float* __restrict__ out) {
    // Whole x tile: 16 planes x 16 rows x 64 floats = 65536 B.
    // Reused after compute as the output bounce buffer.
    __shared__ float xs[16 * 16 * 64];

    int bx   = blockIdx.x;
    int br   = bx / NTILES;
    int tile = bx - br * NTILES;
    int lane = threadIdx.x & 63;
    int wave = threadIdx.x >> 6;
    int l15  = lane & 15;
    int quad = lane >> 4;
    int n    = wave * 16 + l15;  // weight-fragment row: output channel block

    const float* x    = (br == 0) ? x0 : ((br == 1) ? x1 : x2);
    const float* w    = (br == 0) ? w0 : ((br == 1) ? w1 : w2);
    const float* bias = (br == 0) ? b0 : ((br == 1) ? b1 : b2);
    float* outb = out + (size_t)br * OUT_PER_BRANCH;

    // Staging lane decomposition: inst covers 4 site-rows of one plane (1KB);
    // lane serves sub-row (lane>>4), 16B column (lane&15). Global read is
    // LINEAR (perfect 1KB/inst); the XOR swizzle is applied at the ds_write
    // address (logical 16B slot c of row s stored at c ^ (s&7)).
    int sub  = lane >> 4;   // 0..3: which of the 4 rows in this inst
    int lcol = lane & 15;   // 16B column within the 256B row

    int k0 = wave * 16 + quad * 4;

    floatx4 acc[16];  // zero-init AFTER staging (register-pressure window)

    // --- bias + ALL weight fragments into registers, issued BEFORE the x
    // loads so the counted vmcnt waits cover them (in-order retirement). ---
    floatx4 bias4 = *reinterpret_cast<const floatx4*>(bias + k0);
    bf16x8 wf[32];
    if (USE_WT) {
#pragma unroll
        for (int t = 0; t < 16; t++) {
            const bf16x8* wv = reinterpret_cast<const bf16x8*>(
                wT + (((size_t)(br * 16 + t) * 64 + n) * 64) + quad * 8);
            wf[2 * t]     = wv[0];
            wf[2 * t + 1] = wv[4];  // +32 c elements
        }
    } else {
#pragma unroll
        for (int t = 0; t < 16; t++) {
#pragma unroll
            for (int j = 0; j < 8; j++) {
                int c0 = quad * 8 + j;
                wf[2 * t][j]     = f32_to_bf16_bits(w[(t * 64 + c0) * 64 + n]);
                wf[2 * t + 1][j] = f32_to_bf16_bits(w[(t * 64 + c0 + 32) * 64 + n]);
            }
        }
    }
    __builtin_amdgcn_sched_barrier(0);  // pin bias+wf loads first

    // --- x loads into registers: 16 dwordx4/wave. Wave stages planes
    // (4g + wave); inst (g,r) covers site-rows 4r..4r+3 of that plane. ---
    const float* xg = x + (size_t)(tile * 16) * 64;
    floatx4 xa[8], xb[8];
#pragma unroll
    for (int i = 0; i < 8; i++) {  // half A: g = 0,1 (planes for t-half 0)
        int plane = 4 * (i >> 2) + wave;
        int s     = 4 * (i & 3) + sub;
        xa[i] = *(const floatx4*)(xg + ((size_t)plane * NSITES + s) * 64 + lcol * 4);
    }
    __builtin_amdgcn_sched_barrier(0);
#pragma unroll
    for (int i = 0; i < 8; i++) {  // half B: g = 2,3
        int plane = 4 * ((i >> 2) + 2) + wave;
        int s     = 4 * (i & 3) + sub;
        xb[i] = *(const floatx4*)(xg + ((size_t)plane * NSITES + s) * 64 + lcol * 4);
    }
    __builtin_amdgcn_sched_barrier(0);

    // --- compute half h (t = 8h..8h+7): weights from wf regs, ZERO VMEM.
    // Read with the swizzle: logical slot c of row l15 at c ^ (l15&7).
#define COMPUTEHALF(h)                                                         \
    {                                                                          \
        int xr7 = l15 & 7;                                                     \
        _Pragma("unroll") for (int tl = 0; tl < 8; tl++) {                     \
            int t = 8 * (h) + tl;                                              \
            const float* rp = &xs[(t * 16 + l15) * 64];                        \
            floatx4 f0 = *(const floatx4*)(rp + ((quad * 2) ^ xr7) * 4);       \
            floatx4 f1 = *(const floatx4*)(rp + ((quad * 2 + 1) ^ xr7) * 4);   \
            floatx4 f2 = *(const floatx4*)(rp + (((quad * 2) ^ xr7) + 8) * 4); \
            floatx4 f3 = *(const floatx4*)(rp + (((quad * 2 + 1) ^ xr7) + 8) * 4); \
            bf16x8 a0, a1;                                                     \
            _Pragma("unroll") for (int j = 0; j < 4; j++) {                    \
                a0[j]     = f32_to_bf16_bits(f0[j]);                           \
                a0[j + 4] = f32_to_bf16_bits(f1[j]);                           \
                a1[j]     = f32_to_bf16_bits(f2[j]);                           \
                a1[j + 4] = f32_to_bf16_bits(f3[j]);                           \
            }                                                                  \
            acc[t] = __builtin_amdgcn_mfma_f32_16x16x32_bf16(wf[2 * t], a0,    \
                                                             acc[t], 0, 0, 0); \
            acc[t] = __builtin_amdgcn_mfma_f32_16x16x32_bf16(wf[2 * t + 1], a1,\
                                                             acc[t], 0, 0, 0); \
        }                                                                      \
    }

    // --- wait wf + xA (outstanding 48; xA#8 done <=> <=8 remain), write A ---
    asm volatile("s_waitcnt vmcnt(8)" ::: "memory");
    __builtin_amdgcn_sched_barrier(0);
#pragma unroll
    for (int i = 0; i < 8; i++) {
        int plane = 4 * (i >> 2) + wave;
        int s     = 4 * (i & 3) + sub;
        *(floatx4*)&xs[(plane * 16 + s) * 64 + ((lcol ^ (s & 7)) << 2)] = xa[i];
    }
    asm volatile("s_waitcnt lgkmcnt(0)" ::: "memory");
    __builtin_amdgcn_s_barrier();
    __builtin_amdgcn_sched_barrier(0);

#pragma unroll
    for (int t = 0; t < 16; t++) acc[t] = (floatx4){0.f, 0.f, 0.f, 0.f};

    COMPUTEHALF(0);  // x half B still in flight underneath

    // --- xB landed, write planes 8-15 (disjoint from half0 reads) ---
    asm volatile("s_waitcnt vmcnt(0)" ::: "memory");
    __builtin_amdgcn_sched_barrier(0);
#pragma unroll
    for (int i = 0; i < 8; i++) {
        int plane = 4 * ((i >> 2) + 2) + wave;
        int s     = 4 * (i & 3) + sub;
        *(floatx4*)&xs[(plane * 16 + s) * 64 + ((lcol ^ (s & 7)) << 2)] = xb[i];
    }
    asm volatile("s_waitcnt lgkmcnt(0)" ::: "memory");
    __builtin_amdgcn_s_barrier();
    __builtin_amdgcn_sched_barrier(0);

    COMPUTEHALF(1);

#undef COMPUTEHALF

    // ================= Epilogue: WHT -> LDS bounce -> 1KB stores ===========

    // Inverse WHT over v (t = 4u+v): acc[4u+q] = sum_v H[q][v] y[4u+v]
#pragma unroll
    for (int u = 0; u < 4; u++) {
        floatx4 y0 = acc[4 * u + 0], y1 = acc[4 * u + 1];
        floatx4 y2 = acc[4 * u + 2], y3 = acc[4 * u + 3];
        floatx4 A = y0 + y2, Bv = y1 + y3, Cv = y0 - y2, Dv = y1 - y3;
        acc[4 * u + 0] = A + Bv;
        acc[4 * u + 1] = A - Bv;
        acc[4 * u + 2] = Cv + Dv;
        acc[4 * u + 3] = Cv - Dv;
    }

    // All waves done reading xs -> safe to reuse as the output bounce.
    __syncthreads();

    // Inverse WHT over u, scale + bias, write to LDS bounce.
    // Row (site=l15, p, q) holds the pixel's 64 channels; this thread owns
    // k-slot (wave*4+quad), stored at physical slot (slot ^ site).
    int slotw = wave * 4 + quad;
#pragma unroll
    for (int q = 0; q < 4; q++) {
        floatx4 z0 = acc[0 + q], z1 = acc[4 + q], z2 = acc[8 + q], z3 = acc[12 + q];
        floatx4 A = z0 + z2, Bv = z1 + z3, Cv = z0 - z2, Dv = z1 - z3;
        floatx4 o[4];
        o[0] = A + Bv;
        o[1] = A - Bv;
        o[2] = Cv + Dv;
        o[3] = Cv - Dv;
#pragma unroll
        for (int p = 0; p < 4; p++) {
            floatx4 v = o[p] * 0.0625f + bias4;
            *reinterpret_cast<floatx4*>(
                &xs[((l15 * 4 + p) * 4 + q) * 64 + ((slotw ^ l15) << 2)]) = v;
        }
    }
    __syncthreads();

    // Contiguous stores: wave handles 16 (site,p) units; each inst is one
    // 1KB contiguous segment (lane l: q = l>>4, ch-slot = l&15 -> +4*lane).
    int slotr = lane & 15;
    int qr    = lane >> 4;
#pragma unroll
    for (int uu = 0; uu < 16; uu++) {
        int sloc = wave * 4 + (uu & 3);  // site within tile (inner: adjacent)
        int p    = uu >> 2;
        int site = tile * 16 + sloc;
        int b    = site / 784;
        int rem  = site - b * 784;
        int i    = rem / 28;
        int j    = rem - i * 28;
        floatx4 v = *reinterpret_cast<const floatx4*>(
            &xs[((sloc * 4 + p) * 4 + qr) * 64 + ((slotr ^ sloc) << 2)]);
        float* dst = outb +
            (((size_t)(b * 112 + 4 * i + p)) * 112 + 4 * j) * 64 + lane * 4;
        *reinterpret_cast<floatx4*>(dst) = v;
    }
}

extern "C" void kernel_launch(void* const* d_in, const int* in_sizes, int n_in,
                              void* d_out, int out_size, void* d_ws, size_t ws_size,
                              hipStream_t stream) {
    const float* x0 = (const float*)d_in[0];
    const float* x1 = (const float*)d_in[1];
    const float* x2 = (const float*)d_in[2];
    const float* w0 = (const float*)d_in[3];
    const float* w1 = (const float*)d_in[4];
    const float* w2 = (const float*)d_in[5];
    const float* b0 = (const float*)d_in[6];
    const float* b1 = (const float*)d_in[7];
    const float* b2 = (const float*)d_in[8];
    float* out = (float*)d_out;
    __hip_bfloat16* wT = (__hip_bfloat16*)d_ws;

    bool use_wt = ws_size >= (size_t)WT_ELEMS * sizeof(__hip_bfloat16);
    if (use_wt) {
        transpose_weights<<<(WT_ELEMS + 255) / 256, 256, 0, stream>>>(w0, w1, w2, wT);
        iwht_kernel<true><<<3 * NTILES, 256, 0, stream>>>(x0, x1, x2, w0, w1, w2, wT,
                                                          b0, b1, b2, out);
    } else {
        iwht_kernel<false><<<3 * NTILES, 256, 0, stream>>>(x0, x1, x2, w0, w1, w2, wT,
                                                           b0, b1, b2, out);
    }
}

// Round 10
// 291.094 us; speedup vs baseline: 1.0451x; 1.0040x over previous
//
#include <hip/hip_runtime.h>
#include <hip/hip_bf16.h>

// IWHT3Layer: 3 branches of (per-coeff matmul [16,12544,64]x[16,64,64]) +
// inverse 2D 4x4 WHT over the 16 coefficients + bias.
// Inputs: float32. Output: float32.
//
// R14 change vs R13 (100us; ledger: load instrument x2, load schedule x7,
// store shape, occupancy, persistence, barriers ALL null at ~2.3TB/s):
// the wall is the BYTES, not the rate. FETCH=77MB vs 154MB unique reads
// shows half of x is L3-resident across graph iterations; the 150MB output
// write stream is what evicts the other half (154+150 > 256MB L3). R11's
// nt-store test of this mechanism was invalid: its stores were scattered
// 16B pieces, and nt bypassed L2 write-merging (WRITE_SIZE 151->203MB).
// Since R12 every store inst is a full-line contiguous 1KB burst
// (WRITE_SIZE bit-exact 150528.0) — the R11 failure mode is structurally
// absent. So: retest nt on exactly this base. ONE change vs R13:
// __builtin_nontemporal_store on the 16 bounce stores (x loads stay
// cached — we WANT x in L3). Everything else byte-identical to R13
// (reg-staged swizzled LDS, wf-hoist ordering, counted vmcnt per m135,
// WHT -> LDS bounce -> 1KB contiguous stores).

typedef __attribute__((ext_vector_type(8))) short bf16x8;   // 8 bf16 (4 VGPRs)
typedef __attribute__((ext_vector_type(4))) float floatx4;  // MFMA C/D

#define NSITES 12544
#define NTILES 784
#define OUT_PER_BRANCH 12845056  // 16*112*112*64
#define WT_ELEMS (3*16*64*64)

__device__ __forceinline__ short f32_to_bf16_bits(float f) {
    __hip_bfloat16 h = __float2bfloat16(f);  // RNE
    return *reinterpret_cast<short*>(&h);
}

__global__ void transpose_weights(const float* __restrict__ w0,
                                  const float* __restrict__ w1,
                                  const float* __restrict__ w2,
                                  __hip_bfloat16* __restrict__ wT) {
    int idx = blockIdx.x * blockDim.x + threadIdx.x;  // [0, 3*16*64*64)
    if (idx >= WT_ELEMS) return;
    int c  = idx & 63;
    int k  = (idx >> 6) & 63;
    int t  = (idx >> 12) & 15;
    int br = idx >> 16;
    const float* w = (br == 0) ? w0 : ((br == 1) ? w1 : w2);
    // wT[br][t][k][c] = bf16(w[br][t][c][k])
    wT[idx] = __float2bfloat16(w[(t * 64 + c) * 64 + k]);
}

template <bool USE_WT>
__global__ __launch_bounds__(256, 2) void iwht_kernel(
    const float* __restrict__ x0, const float* __restrict__ x1,
    const float* __restrict__ x2,
    const float* __restrict__ w0, const float* __restrict__ w1,
    const float* __restrict__ w2,
    const __hip_bfloat16* __restrict__ wT,
    const float* __restrict__ b0, const float* __restrict__ b1,
    const float* __restrict__ b2,
    float* __restrict__ out) {
    // Whole x tile: 16 planes x 16 rows x 64 floats = 65536 B.
    // Reused after compute as the output bounce buffer.
    __shared__ float xs[16 * 16 * 64];

    int bx   = blockIdx.x;
    int br   = bx / NTILES;
    int tile = bx - br * NTILES;
    int lane = threadIdx.x & 63;
    int wave = threadIdx.x >> 6;
    int l15  = lane & 15;
    int quad = lane >> 4;
    int n    = wave * 16 + l15;  // weight-fragment row: output channel block

    const float* x    = (br == 0) ? x0 : ((br == 1) ? x1 : x2);
    const float* w    = (br == 0) ? w0 : ((br == 1) ? w1 : w2);
    const float* bias = (br == 0) ? b0 : ((br == 1) ? b1 : b2);
    float* outb = out + (size_t)br * OUT_PER_BRANCH;

    // Staging lane decomposition: inst covers 4 site-rows of one plane (1KB);
    // lane serves sub-row (lane>>4), 16B column (lane&15). Global read is
    // LINEAR (perfect 1KB/inst); the XOR swizzle is applied at the ds_write
    // address (logical 16B slot c of row s stored at c ^ (s&7)).
    int sub  = lane >> 4;   // 0..3: which of the 4 rows in this inst
    int lcol = lane & 15;   // 16B column within the 256B row

    int k0 = wave * 16 + quad * 4;

    floatx4 acc[16];  // zero-init AFTER staging (register-pressure window)

    // --- bias + ALL weight fragments into registers, issued BEFORE the x
    // loads so the counted vmcnt waits cover them (in-order retirement). ---
    floatx4 bias4 = *reinterpret_cast<const floatx4*>(bias + k0);
    bf16x8 wf[32];
    if (USE_WT) {
#pragma unroll
        for (int t = 0; t < 16; t++) {
            const bf16x8* wv = reinterpret_cast<const bf16x8*>(
                wT + (((size_t)(br * 16 + t) * 64 + n) * 64) + quad * 8);
            wf[2 * t]     = wv[0];
            wf[2 * t + 1] = wv[4];  // +32 c elements
        }
    } else {
#pragma unroll
        for (int t = 0; t < 16; t++) {
#pragma unroll
            for (int j = 0; j < 8; j++) {
                int c0 = quad * 8 + j;
                wf[2 * t][j]     = f32_to_bf16_bits(w[(t * 64 + c0) * 64 + n]);
                wf[2 * t + 1][j] = f32_to_bf16_bits(w[(t * 64 + c0 + 32) * 64 + n]);
            }
        }
    }
    __builtin_amdgcn_sched_barrier(0);  // pin bias+wf loads first

    // --- x loads into registers: 16 dwordx4/wave. Wave stages planes
    // (4g + wave); inst (g,r) covers site-rows 4r..4r+3 of that plane. ---
    const float* xg = x + (size_t)(tile * 16) * 64;
    floatx4 xa[8], xb[8];
#pragma unroll
    for (int i = 0; i < 8; i++) {  // half A: g = 0,1 (planes for t-half 0)
        int plane = 4 * (i >> 2) + wave;
        int s     = 4 * (i & 3) + sub;
        xa[i] = *(const floatx4*)(xg + ((size_t)plane * NSITES + s) * 64 + lcol * 4);
    }
    __builtin_amdgcn_sched_barrier(0);
#pragma unroll
    for (int i = 0; i < 8; i++) {  // half B: g = 2,3
        int plane = 4 * ((i >> 2) + 2) + wave;
        int s     = 4 * (i & 3) + sub;
        xb[i] = *(const floatx4*)(xg + ((size_t)plane * NSITES + s) * 64 + lcol * 4);
    }
    __builtin_amdgcn_sched_barrier(0);

    // --- compute half h (t = 8h..8h+7): weights from wf regs, ZERO VMEM.
    // Read with the swizzle: logical slot c of row l15 at c ^ (l15&7).
#define COMPUTEHALF(h)                                                         \
    {                                                                          \
        int xr7 = l15 & 7;                                                     \
        _Pragma("unroll") for (int tl = 0; tl < 8; tl++) {                     \
            int t = 8 * (h) + tl;                                              \
            const float* rp = &xs[(t * 16 + l15) * 64];                        \
            floatx4 f0 = *(const floatx4*)(rp + ((quad * 2) ^ xr7) * 4);       \
            floatx4 f1 = *(const floatx4*)(rp + ((quad * 2 + 1) ^ xr7) * 4);   \
            floatx4 f2 = *(const floatx4*)(rp + (((quad * 2) ^ xr7) + 8) * 4); \
            floatx4 f3 = *(const floatx4*)(rp + (((quad * 2 + 1) ^ xr7) + 8) * 4); \
            bf16x8 a0, a1;                                                     \
            _Pragma("unroll") for (int j = 0; j < 4; j++) {                    \
                a0[j]     = f32_to_bf16_bits(f0[j]);                           \
                a0[j + 4] = f32_to_bf16_bits(f1[j]);                           \
                a1[j]     = f32_to_bf16_bits(f2[j]);                           \
                a1[j + 4] = f32_to_bf16_bits(f3[j]);                           \
            }                                                                  \
            acc[t] = __builtin_amdgcn_mfma_f32_16x16x32_bf16(wf[2 * t], a0,    \
                                                             acc[t], 0, 0, 0); \
            acc[t] = __builtin_amdgcn_mfma_f32_16x16x32_bf16(wf[2 * t + 1], a1,\
                                                             acc[t], 0, 0, 0); \
        }                                                                      \
    }

    // --- wait wf + xA (outstanding 48; xA#8 done <=> <=8 remain), write A ---
    asm volatile("s_waitcnt vmcnt(8)" ::: "memory");
    __builtin_amdgcn_sched_barrier(0);
#pragma unroll
    for (int i = 0; i < 8; i++) {
        int plane = 4 * (i >> 2) + wave;
        int s     = 4 * (i & 3) + sub;
        *(floatx4*)&xs[(plane * 16 + s) * 64 + ((lcol ^ (s & 7)) << 2)] = xa[i];
    }
    asm volatile("s_waitcnt lgkmcnt(0)" ::: "memory");
    __builtin_amdgcn_s_barrier();
    __builtin_amdgcn_sched_barrier(0);

#pragma unroll
    for (int t = 0; t < 16; t++) acc[t] = (floatx4){0.f, 0.f, 0.f, 0.f};

    COMPUTEHALF(0);  // x half B still in flight underneath

    // --- xB landed, write planes 8-15 (disjoint from half0 reads) ---
    asm volatile("s_waitcnt vmcnt(0)" ::: "memory");
    __builtin_amdgcn_sched_barrier(0);
#pragma unroll
    for (int i = 0; i < 8; i++) {
        int plane = 4 * ((i >> 2) + 2) + wave;
        int s     = 4 * (i & 3) + sub;
        *(floatx4*)&xs[(plane * 16 + s) * 64 + ((lcol ^ (s & 7)) << 2)] = xb[i];
    }
    asm volatile("s_waitcnt lgkmcnt(0)" ::: "memory");
    __builtin_amdgcn_s_barrier();
    __builtin_amdgcn_sched_barrier(0);

    COMPUTEHALF(1);

#undef COMPUTEHALF

    // ================= Epilogue: WHT -> LDS bounce -> 1KB stores ===========

    // Inverse WHT over v (t = 4u+v): acc[4u+q] = sum_v H[q][v] y[4u+v]
#pragma unroll
    for (int u = 0; u < 4; u++) {
        floatx4 y0 = acc[4 * u + 0], y1 = acc[4 * u + 1];
        floatx4 y2 = acc[4 * u + 2], y3 = acc[4 * u + 3];
        floatx4 A = y0 + y2, Bv = y1 + y3, Cv = y0 - y2, Dv = y1 - y3;
        acc[4 * u + 0] = A + Bv;
        acc[4 * u + 1] = A - Bv;
        acc[4 * u + 2] = Cv + Dv;
        acc[4 * u + 3] = Cv - Dv;
    }

    // All waves done reading xs -> safe to reuse as the output bounce.
    __syncthreads();

    // Inverse WHT over u, scale + bias, write to LDS bounce.
    // Row (site=l15, p, q) holds the pixel's 64 channels; this thread owns
    // k-slot (wave*4+quad), stored at physical slot (slot ^ site).
    int slotw = wave * 4 + quad;
#pragma unroll
    for (int q = 0; q < 4; q++) {
        floatx4 z0 = acc[0 + q], z1 = acc[4 + q], z2 = acc[8 + q], z3 = acc[12 + q];
        floatx4 A = z0 + z2, Bv = z1 + z3, Cv = z0 - z2, Dv = z1 - z3;
        floatx4 o[4];
        o[0] = A + Bv;
        o[1] = A - Bv;
        o[2] = Cv + Dv;
        o[3] = Cv - Dv;
#pragma unroll
        for (int p = 0; p < 4; p++) {
            floatx4 v = o[p] * 0.0625f + bias4;
            *reinterpret_cast<floatx4*>(
                &xs[((l15 * 4 + p) * 4 + q) * 64 + ((slotw ^ l15) << 2)]) = v;
        }
    }
    __syncthreads();

    // Contiguous NONTEMPORAL stores: wave handles 16 (site,p) units; each
    // inst is one full-line contiguous 1KB segment (lane l: q = l>>4,
    // ch-slot = l&15 -> +4*lane). nt = no L3 allocation -> x stays resident.
    int slotr = lane & 15;
    int qr    = lane >> 4;
#pragma unroll
    for (int uu = 0; uu < 16; uu++) {
        int sloc = wave * 4 + (uu & 3);  // site within tile (inner: adjacent)
        int p    = uu >> 2;
        int site = tile * 16 + sloc;
        int b    = site / 784;
        int rem  = site - b * 784;
        int i    = rem / 28;
        int j    = rem - i * 28;
        floatx4 v = *reinterpret_cast<const floatx4*>(
            &xs[((sloc * 4 + p) * 4 + qr) * 64 + ((slotr ^ sloc) << 2)]);
        float* dst = outb +
            (((size_t)(b * 112 + 4 * i + p)) * 112 + 4 * j) * 64 + lane * 4;
        __builtin_nontemporal_store(v, reinterpret_cast<floatx4*>(dst));
    }
}

extern "C" void kernel_launch(void* const* d_in, const int* in_sizes, int n_in,
                              void* d_out, int out_size, void* d_ws, size_t ws_size,
                              hipStream_t stream) {
    const float* x0 = (const float*)d_in[0];
    const float* x1 = (const float*)d_in[1];
    const float* x2 = (const float*)d_in[2];
    const float* w0 = (const float*)d_in[3];
    const float* w1 = (const float*)d_in[4];
    const float* w2 = (const float*)d_in[5];
    const float* b0 = (const float*)d_in[6];
    const float* b1 = (const float*)d_in[7];
    const float* b2 = (const float*)d_in[8];
    float* out = (float*)d_out;
    __hip_bfloat16* wT = (__hip_bfloat16*)d_ws;

    bool use_wt = ws_size >= (size_t)WT_ELEMS * sizeof(__hip_bfloat16);
    if (use_wt) {
        transpose_weights<<<(WT_ELEMS + 255) / 256, 256, 0, stream>>>(w0, w1, w2, wT);
        iwht_kernel<true><<<3 * NTILES, 256, 0, stream>>>(x0, x1, x2, w0, w1, w2, wT,
                                                          b0, b1, b2, out);
    } else {
        iwht_kernel<false><<<3 * NTILES, 256, 0, stream>>>(x0, x1, x2, w0, w1, w2, wT,
                                                           b0, b1, b2, out);
    }
}